// Round 6
// baseline (175.211 us; speedup 1.0000x reference)
//
#include <hip/hip_runtime.h>
#include <stdint.h>

// S=512, B=64, H=8, K=12, P=9, L=137, T=4096, THRESH=4
// Workspace layout (u32 units):
//   WS_TABLE [0, 65536)        packed ram tables: 128 u32 per hb      = 256 KB
//   WS_AK    [65536, 196608)   Ak partial addrs: 512 u16 per hb       = 512 KB
//   WS_AQ    [196608, 327680)  Aq partial addrs: 512 u16 per hb       = 512 KB
//   WS_PAR   [327680, 335872)  parity bits: [hb][chunk(8)][2] u32     = 32 KB
//   WS_TOK   [335872, 336896)  packed token rows: 512 u64             = 4 KB
//   WS_FLAG  [336896, 337408)  1 = slow path, 0 = fast path           = 2 KB
#define WS_TABLE 0
#define WS_AK    65536
#define WS_AQ    196608
#define WS_PAR   327680
#define WS_TOK   335872
#define WS_FLAG  336896

// ---- Kernel 0: pack ram bit-tables + Aq/Ak arrays + token-row bitmasks ----
__global__ __launch_bounds__(256) void softram_pack_kernel(
    const int* __restrict__ tokens,   // (512, 64)
    const int* __restrict__ conn,     // (8, 64, 12)
    const float* __restrict__ ram,    // (8, 64, 4096) values in {0,1}
    uint32_t* __restrict__ ws)
{
    const int tid = threadIdx.x, lane = tid & 63, w = tid >> 6;
    if (blockIdx.x < 512) {
        const int hb = blockIdx.x;
        const float* ramp = ram + (size_t)hb * 4096;
        uint32_t* tp = ws + WS_TABLE + hb * 128;
        #pragma unroll
        for (int c = 0; c < 16; ++c) {
            float v = ramp[c * 256 + tid];
            unsigned long long m = __ballot(v > 0.5f);
            if (lane == 0) {
                tp[c * 8 + w * 2]     = (uint32_t)m;
                tp[c * 8 + w * 2 + 1] = (uint32_t)(m >> 32);
            }
        }
    } else if (blockIdx.x < 1024) {
        const int hb = blockIdx.x - 512;
        const int* cp = conn + hb * 12;          // uniform -> scalar loads
        int ck[12];
        #pragma unroll
        for (int k = 0; k < 12; ++k) ck[k] = cp[k];
        unsigned short* akg = (unsigned short*)(ws + WS_AK) + hb * 512;
        unsigned short* aqg = (unsigned short*)(ws + WS_AQ) + hb * 512;
        #pragma unroll
        for (int rep = 0; rep < 2; ++rep) {
            int s = tid + rep * 256;
            int aq = 0, ak = 0;
            #pragma unroll
            for (int k = 0; k < 12; ++k) {
                int c = ck[k];                    // wave-uniform branch
                if (c < 64)       aq |= tokens[s * 64 + c] << k;
                else if (c < 128) ak |= tokens[s * 64 + (c - 64)] << k;
            }
            aqg[s] = (unsigned short)aq;
            akg[s] = (unsigned short)ak;
        }
    } else {                                     // 32 blocks: token-row bitmasks
        const int r = blockIdx.x - 1024;
        unsigned long long* tokp = (unsigned long long*)(ws + WS_TOK);
        #pragma unroll
        for (int g = 0; g < 16; ++g) {
            int c = r * 16 + g;                  // s = c*4 + w, bit = lane (=col b)
            int v = tokens[c * 256 + tid];
            unsigned long long m = __ballot(v != 0);
            if (lane == 0) tokp[c * 4 + w] = m;
        }
    }
}

// ---- fast-path row phase, templated on T-row word count (inlined: LDS!) ----
template<int W64>
__device__ __forceinline__ void fast_rows(
    int hb, int lane, const int* ck, const unsigned long long* TL,
    const unsigned long long* tokp, uint32_t* wp)
{
    unsigned long long carry[W64];
    #pragma unroll
    for (int wd = 0; wd < W64; ++wd) carry[wd] = 0ull;

    for (int g = 0; g < 8; ++g) {
        int i = g * 64 + lane;
        unsigned long long row = tokp[i];        // coalesced global u64
        int aqc = 0, akc = 0, qc = 0, kc = 0;
        #pragma unroll
        for (int k = 0; k < 12; ++k) {
            int cv = ck[k];                      // wave-uniform branch
            if (cv < 64)       { aqc |= (int)((row >> cv) & 1ull) << qc; ++qc; }
            else if (cv < 128) { akc |= (int)((row >> (cv - 64)) & 1ull) << kc; ++kc; }
        }
        // one-hot of akc, then inclusive wave prefix-XOR
        unsigned long long X[W64];
        #pragma unroll
        for (int wd = 0; wd < W64; ++wd)
            X[wd] = (wd == (akc >> 6)) ? (1ull << (akc & 63)) : 0ull;
        #pragma unroll
        for (int off = 1; off < 64; off <<= 1) {
            #pragma unroll
            for (int wd = 0; wd < W64; ++wd) {
                unsigned long long t = __shfl_up(X[wd], off);
                if (lane >= off) X[wd] ^= t;
            }
        }
        int pc = 0;
        #pragma unroll
        for (int wd = 0; wd < W64; ++wd)
            pc += __popcll(TL[aqc * W64 + wd] & (carry[wd] ^ X[wd]));
        unsigned long long m = __ballot(pc & 1);
        if (lane == 0) {
            wp[(hb * 8 + g) * 2]     = (uint32_t)m;
            wp[(hb * 8 + g) * 2 + 1] = (uint32_t)(m >> 32);
        }
        #pragma unroll
        for (int wd = 0; wd < W64; ++wd) carry[wd] ^= __shfl(X[wd], 63);
    }
}

// ---- Kernel 1: fast path for nr==0 hb's (one block per hb) ----
__global__ __launch_bounds__(256) void softram_fast_kernel(
    const int* __restrict__ conn, uint32_t* __restrict__ ws)
{
    __shared__ uint32_t tblL[128];
    __shared__ unsigned long long TL[512];       // permuted table, <= 4 KB

    const int tid = threadIdx.x, lane = tid & 63, w = tid >> 6;
    const int hb  = blockIdx.x;

    const int* cp = conn + hb * 12;
    int ck[12];
    #pragma unroll
    for (int k = 0; k < 12; ++k) ck[k] = cp[k];
    int nq = 0, nk = 0, nr = 0;
    #pragma unroll
    for (int k = 0; k < 12; ++k) {
        int cv = ck[k];
        if (cv < 64) ++nq; else if (cv < 128) ++nk; else ++nr;
    }
    const bool fast = (nr == 0) && (nk >= 3) && (nk <= 8);
    if (tid == 0) ws[WS_FLAG + hb] = fast ? 0u : 1u;
    if (!fast) return;                           // uniform per block

    if (tid < 128) tblL[tid] = ws[WS_TABLE + hb * 128 + tid];
    __syncthreads();

    // build permuted table T: row a (compact q) x col m (compact k)
    const int rsh  = (nk > 6) ? (nk - 6) : 0;    // words per row = 1<<rsh
    const int Wtot = (1 << nq) << rsh;
    for (int wi = w; wi < Wtot; wi += 4) {
        int a  = wi >> rsh;
        int mw = wi & ((1 << rsh) - 1);
        int m  = (mw << 6) | lane;
        int spread = 0, qc = 0, kc = 0;
        #pragma unroll
        for (int k = 0; k < 12; ++k) {
            int cv = ck[k];
            if (cv < 64)       { spread |= ((a >> qc) & 1) << k; ++qc; }
            else if (cv < 128) { spread |= ((m >> kc) & 1) << k; ++kc; }
        }
        int bit = (m < (1 << nk)) ? (int)((tblL[spread >> 5] >> (spread & 31)) & 1u) : 0;
        unsigned long long bm = __ballot(bit != 0);
        if (lane == 0) TL[wi] = bm;
    }
    __syncthreads();

    if (w == 0) {
        const unsigned long long* tokp = (const unsigned long long*)(ws + WS_TOK);
        uint32_t* wp = ws + WS_PAR;
        if (nk <= 6)      fast_rows<1>(hb, lane, ck, TL, tokp, wp);
        else if (nk == 7) fast_rows<2>(hb, lane, ck, TL, tokp, wp);
        else              fast_rows<4>(hb, lane, ck, TL, tokp, wp);
    }
}

// ---- Kernel 2: slow parity (R4 structure, lean r-compute, flag early-exit) ----
__global__ __launch_bounds__(256) void softram_parity_kernel(
    const int* __restrict__ conn, uint32_t* __restrict__ ws)
{
    __shared__ uint32_t tbl[128];
    __shared__ unsigned short AkL[512];
    __shared__ unsigned short ArL[512];
    __shared__ unsigned long long parbuf[2][4];

    const int tid  = threadIdx.x;
    const int lane = tid & 63;
    const int w    = tid >> 6;
    const int hb   = blockIdx.x >> 2;
    const int q    = blockIdx.x & 3;

    if (ws[WS_FLAG + hb] == 0u) return;          // fast path handled it

    if (tid < 128) tbl[tid] = ws[WS_TABLE + hb * 128 + tid];
    ((uint32_t*)AkL)[tid] = ws[WS_AK + hb * 256 + tid];

    const int* cp = conn + hb * 12;
    int ck[12];
    #pragma unroll
    for (int k = 0; k < 12; ++k) ck[k] = cp[k];
    // p=15 neutralizes unused r-slots: d < 512 so (d>>15)&1 == 0
    int p0 = 15, k0 = 0, p1 = 15, k1 = 0, nr = 0;
    #pragma unroll
    for (int k = 0; k < 12; ++k) {
        int cv = ck[k];
        if (cv >= 128) {
            if (nr == 0)      { p0 = cv - 128; k0 = k; }
            else if (nr == 1) { p1 = cv - 128; k1 = k; }
            ++nr;
        }
    }

    // ArL for the generic (nr>=3) fallback
    #pragma unroll
    for (int rep = 0; rep < 2; ++rep) {
        int s = tid + rep * 256;
        int ar = 0;
        #pragma unroll
        for (int k = 0; k < 12; ++k) {
            int cv = ck[k];
            if (cv >= 128) ar += ((s >> (cv - 128)) & 1) << k;
        }
        ArL[s] = (unsigned short)ar;
    }
    __syncthreads();

    const unsigned short* aqg = (const unsigned short*)(ws + WS_AQ) + hb * 512;
    const int chunks[2] = { q, 7 - q };
    uint32_t accs[2];

    for (int ci = 0; ci < 2; ++ci) {
        const int c  = chunks[ci];
        const int aq = (int)aqg[c * 64 + lane];
        uint32_t acc = 0;
        if (nr <= 2) {
            for (int sb = w; sb < c; sb += 4) {  // full sub-blocks, d >= 1
                int akv = (int)AkL[sb * 64 + lane];
                int dbase = (c - sb) * 64 + lane;
                #pragma unroll
                for (int jj = 0; jj < 64; ++jj) {
                    int sak = __builtin_amdgcn_readlane(akv, jj);
                    int d = dbase - jj;
                    int addr = aq + sak + (((d >> p0) & 1) << k0)
                                        + (((d >> p1) & 1) << k1);
                    acc ^= tbl[addr >> 5] >> (addr & 31);   // parity in bit 0
                }
            }
            if (w == (c & 3)) {                  // tail sub-block sb == c
                int akv = (int)AkL[c * 64 + lane];
                #pragma unroll
                for (int jj = 0; jj < 64; ++jj) {
                    int sak = __builtin_amdgcn_readlane(akv, jj);
                    int d = lane - jj;           // may be < 0
                    int dm = d & ~(d >> 31);     // max(d, 0)
                    int addr = aq + sak + (((dm >> p0) & 1) << k0)
                                        + (((dm >> p1) & 1) << k1);
                    uint32_t keep = ~(uint32_t)(d >> 31);   // 0 if d < 0
                    acc ^= (tbl[addr >> 5] >> (addr & 31)) & keep;
                }
            }
        } else {                                 // rare: Ar via LDS
            for (int sb = w; sb <= c; sb += 4) {
                int akv = (int)AkL[sb * 64 + lane];
                int dbase = (c - sb) * 64 + lane;
                #pragma unroll 8
                for (int jj = 0; jj < 64; ++jj) {
                    int sak = __builtin_amdgcn_readlane(akv, jj);
                    int d = dbase - jj;
                    int dm = d & ~(d >> 31);
                    int addr = aq + sak + (int)ArL[dm];
                    uint32_t keep = ~(uint32_t)(d >> 31);
                    acc ^= (tbl[addr >> 5] >> (addr & 31)) & keep;
                }
            }
        }
        accs[ci] = acc & 1u;
    }

    #pragma unroll
    for (int ci = 0; ci < 2; ++ci) {
        unsigned long long m = __ballot(accs[ci] != 0);
        if (lane == 0) parbuf[ci][w] = m;
    }
    __syncthreads();

    if (tid == 0) {
        uint32_t* wp = ws + WS_PAR;
        #pragma unroll
        for (int ci = 0; ci < 2; ++ci) {
            int c = chunks[ci];
            unsigned long long m = parbuf[ci][0] ^ parbuf[ci][1]
                                 ^ parbuf[ci][2] ^ parbuf[ci][3];
            wp[(hb * 8 + c) * 2]     = (uint32_t)m;
            wp[(hb * 8 + c) * 2 + 1] = (uint32_t)(m >> 32);
        }
    }
}

// ---- Kernel 3: majority vote over heads ----
__global__ __launch_bounds__(256) void softram_vote_kernel(
    const uint32_t* __restrict__ ws, float* __restrict__ out)
{
    int t = blockIdx.x * 256 + threadIdx.x;      // t = i*64 + b
    int b = t & 63;
    int i = t >> 6;
    const uint32_t* wp = ws + WS_PAR;
    int sum = 0;
    #pragma unroll
    for (int h = 0; h < 8; ++h) {
        int hb = h * 64 + b;
        uint32_t wv = wp[(hb * 8 + (i >> 6)) * 2 + ((i >> 5) & 1)];
        sum += (wv >> (i & 31)) & 1u;
    }
    out[t] = (sum > 4) ? 1.0f : 0.0f;            // THRESH = H/2 = 4
}

extern "C" void kernel_launch(void* const* d_in, const int* in_sizes, int n_in,
                              void* d_out, int out_size, void* d_ws, size_t ws_size,
                              hipStream_t stream) {
    const int*   tokens = (const int*)d_in[0];   // (512, 64)
    const int*   conn   = (const int*)d_in[1];   // (8, 64, 12)
    const float* ram    = (const float*)d_in[2]; // (8, 64, 4096)
    float*       out    = (float*)d_out;         // (512, 64)
    uint32_t*    ws     = (uint32_t*)d_ws;       // ~1.35 MB used

    softram_pack_kernel<<<1056, 256, 0, stream>>>(tokens, conn, ram, ws);
    softram_fast_kernel<<<512, 256, 0, stream>>>(conn, ws);
    softram_parity_kernel<<<2048, 256, 0, stream>>>(conn, ws);
    softram_vote_kernel<<<128, 256, 0, stream>>>(ws, out);
}

// Round 7
// 109.655 us; speedup vs baseline: 1.5978x; 1.5978x over previous
//
#include <hip/hip_runtime.h>
#include <stdint.h>

// S=512, B=64, H=8, K=12, P=9, L=137, T=4096, THRESH=4
// Workspace layout (u32 units):
//   WS_TABLE [0, 65536)       packed ram tables: 128 u32 per hb   = 256 KB
//   WS_TOK   [65536, 66560)   packed token rows: 512 u64          = 4 KB
//   WS_PAR   [66560, 74752)   parity bits: [hb][chunk(8)][2] u32  = 32 KB
#define WS_TABLE 0
#define WS_TOK   65536
#define WS_PAR   66560

// ---- Kernel 0: pack ram bit-tables (512 blocks) + token bitmasks (32) ----
__global__ __launch_bounds__(256) void softram_pack_kernel(
    const int* __restrict__ tokens,   // (512, 64)
    const float* __restrict__ ram,    // (8, 64, 4096) values in {0,1}
    uint32_t* __restrict__ ws)
{
    const int tid = threadIdx.x, lane = tid & 63, w = tid >> 6;
    if (blockIdx.x < 512) {
        const int hb = blockIdx.x;
        const float* ramp = ram + (size_t)hb * 4096;
        uint32_t* tp = ws + WS_TABLE + hb * 128;
        #pragma unroll
        for (int c = 0; c < 16; ++c) {
            float v = ramp[c * 256 + tid];
            unsigned long long m = __ballot(v > 0.5f);
            if (lane == 0) {
                tp[c * 8 + w * 2]     = (uint32_t)m;
                tp[c * 8 + w * 2 + 1] = (uint32_t)(m >> 32);
            }
        }
    } else {                                     // 32 blocks: token-row bitmasks
        const int r = blockIdx.x - 512;          // c in [0,128): s = c*4 + w
        unsigned long long* tokp = (unsigned long long*)(ws + WS_TOK);
        #pragma unroll
        for (int g = 0; g < 4; ++g) {
            int c = r * 4 + g;
            int v = tokens[c * 256 + tid];       // bit index = lane (= col b)
            unsigned long long m = __ballot(v != 0);
            if (lane == 0) tokp[c * 4 + w] = m;
        }
    }
}

// ---- Kernel 1: parity. 4 blocks per hb (block q owns chunks {q, 7-q});
//      sub-blocks split mod 4 across the 4 waves. Fully inlined:
//      table reads MUST stay ds_read_b32 (R3 lesson: no noinline/flat). ----
__global__ __launch_bounds__(256) void softram_parity_kernel(
    const int* __restrict__ conn,     // (8, 64, 12)
    uint32_t* __restrict__ ws)
{
    __shared__ uint32_t tbl[128];                // bit-packed 4096-bit table
    __shared__ unsigned short AqL[512], AkL[512], ArL[512];
    __shared__ unsigned long long parbuf[2][4];

    const int tid  = threadIdx.x;
    const int lane = tid & 63;
    const int w    = tid >> 6;
    const int hb   = blockIdx.x >> 2;
    const int q    = blockIdx.x & 3;

    if (tid < 128) tbl[tid] = ws[WS_TABLE + hb * 128 + tid];

    // wave-uniform conn info (scalar loads)
    const int* cp = conn + hb * 12;
    int ck[12];
    #pragma unroll
    for (int k = 0; k < 12; ++k) ck[k] = cp[k];
    // p=15 neutralizes unused r-slots: d < 512 so (d>>15)&1 == 0
    int p0 = 15, k0 = 0, p1 = 15, k1 = 0, nr = 0;
    #pragma unroll
    for (int k = 0; k < 12; ++k) {
        int cv = ck[k];
        if (cv >= 128) {
            if (nr == 0)      { p0 = cv - 128; k0 = k; }
            else if (nr == 1) { p1 = cv - 128; k1 = k; }
            ++nr;
        }
    }

    // per-position partial addresses from packed token rows (coalesced u64)
    const unsigned long long* tokp = (const unsigned long long*)(ws + WS_TOK);
    #pragma unroll
    for (int rep = 0; rep < 2; ++rep) {
        int s = tid + rep * 256;
        unsigned long long row = tokp[s];
        int aq = 0, ak = 0, ar = 0;
        #pragma unroll
        for (int k = 0; k < 12; ++k) {
            int cv = ck[k];                      // wave-uniform branch
            if (cv < 64)       aq |= (int)((row >> cv) & 1ull) << k;
            else if (cv < 128) ak |= (int)((row >> (cv - 64)) & 1ull) << k;
            else               ar += ((s >> (cv - 128)) & 1) << k;
        }
        AqL[s] = (unsigned short)aq;
        AkL[s] = (unsigned short)ak;
        ArL[s] = (unsigned short)ar;
    }
    __syncthreads();

    const int chunks[2] = { q, 7 - q };
    uint32_t accs[2];

    for (int ci = 0; ci < 2; ++ci) {
        const int c  = chunks[ci];
        const int aq = (int)AqL[c * 64 + lane];
        uint32_t acc = 0;
        if (nr <= 2) {                           // 96.6% of hb: r-part in VALU
            for (int sb = w; sb < c; sb += 4) {  // full sub-blocks, d >= 1
                int akv = (int)AkL[sb * 64 + lane];
                int dbase = (c - sb) * 64 + lane;
                #pragma unroll
                for (int jj = 0; jj < 64; ++jj) {
                    int sak = __builtin_amdgcn_readlane(akv, jj);
                    int d = dbase - jj;
                    int addr = aq + sak + (((d >> p0) & 1) << k0)
                                        + (((d >> p1) & 1) << k1);
                    acc ^= tbl[addr >> 5] >> (addr & 31);   // parity in bit 0
                }
            }
            if (w == (c & 3)) {                  // tail sub-block sb == c
                int akv = (int)AkL[c * 64 + lane];
                #pragma unroll
                for (int jj = 0; jj < 64; ++jj) {
                    int sak = __builtin_amdgcn_readlane(akv, jj);
                    int d = lane - jj;           // may be < 0
                    int dm = d & ~(d >> 31);     // max(d, 0)
                    int addr = aq + sak + (((dm >> p0) & 1) << k0)
                                        + (((dm >> p1) & 1) << k1);
                    uint32_t keep = ~(uint32_t)(d >> 31);   // 0 if d < 0
                    acc ^= (tbl[addr >> 5] >> (addr & 31)) & keep;
                }
            }
        } else {                                 // rare (3.4%): Ar via LDS
            for (int sb = w; sb <= c; sb += 4) {
                int akv = (int)AkL[sb * 64 + lane];
                int dbase = (c - sb) * 64 + lane;
                #pragma unroll 8
                for (int jj = 0; jj < 64; ++jj) {
                    int sak = __builtin_amdgcn_readlane(akv, jj);
                    int d = dbase - jj;
                    int dm = d & ~(d >> 31);
                    int addr = aq + sak + (int)ArL[dm];
                    uint32_t keep = ~(uint32_t)(d >> 31);
                    acc ^= (tbl[addr >> 5] >> (addr & 31)) & keep;
                }
            }
        }
        accs[ci] = acc & 1u;
    }

    #pragma unroll
    for (int ci = 0; ci < 2; ++ci) {
        unsigned long long m = __ballot(accs[ci] != 0);
        if (lane == 0) parbuf[ci][w] = m;
    }
    __syncthreads();

    if (tid == 0) {
        uint32_t* wp = ws + WS_PAR;
        #pragma unroll
        for (int ci = 0; ci < 2; ++ci) {
            int c = chunks[ci];
            unsigned long long m = parbuf[ci][0] ^ parbuf[ci][1]
                                 ^ parbuf[ci][2] ^ parbuf[ci][3];
            wp[(hb * 8 + c) * 2]     = (uint32_t)m;
            wp[(hb * 8 + c) * 2 + 1] = (uint32_t)(m >> 32);
        }
    }
}

// ---- Kernel 2: majority vote over heads ----
__global__ __launch_bounds__(256) void softram_vote_kernel(
    const uint32_t* __restrict__ ws, float* __restrict__ out)
{
    int t = blockIdx.x * 256 + threadIdx.x;      // t = i*64 + b
    int b = t & 63;
    int i = t >> 6;
    const uint32_t* wp = ws + WS_PAR;
    int sum = 0;
    #pragma unroll
    for (int h = 0; h < 8; ++h) {
        int hb = h * 64 + b;
        uint32_t wv = wp[(hb * 8 + (i >> 6)) * 2 + ((i >> 5) & 1)];
        sum += (wv >> (i & 31)) & 1u;
    }
    out[t] = (sum > 4) ? 1.0f : 0.0f;            // THRESH = H/2 = 4
}

extern "C" void kernel_launch(void* const* d_in, const int* in_sizes, int n_in,
                              void* d_out, int out_size, void* d_ws, size_t ws_size,
                              hipStream_t stream) {
    const int*   tokens = (const int*)d_in[0];   // (512, 64)
    const int*   conn   = (const int*)d_in[1];   // (8, 64, 12)
    const float* ram    = (const float*)d_in[2]; // (8, 64, 4096)
    float*       out    = (float*)d_out;         // (512, 64)
    uint32_t*    ws     = (uint32_t*)d_ws;       // ~300 KB used

    softram_pack_kernel<<<544, 256, 0, stream>>>(tokens, ram, ws);
    softram_parity_kernel<<<2048, 256, 0, stream>>>(conn, ws);
    softram_vote_kernel<<<128, 256, 0, stream>>>(ws, out);
}